// Round 1
// baseline (346.181 us; speedup 1.0000x reference)
//
#include <hip/hip_runtime.h>
#include <hip/hip_bf16.h>

#define HW_   262144   // 512*512
#define C_    256
#define NP_   64
#define NBLK_ 1024     // HW_/256
#define SENT  3.0e38f

__device__ __forceinline__ void top5_insert(float (&t)[5], float v) {
  if (v < t[4]) {
    t[4] = v;
    if (t[4] < t[3]) { float x = t[3]; t[3] = t[4]; t[4] = x; }
    if (t[3] < t[2]) { float x = t[2]; t[2] = t[3]; t[3] = x; }
    if (t[2] < t[1]) { float x = t[1]; t[1] = t[2]; t[2] = x; }
    if (t[1] < t[0]) { float x = t[0]; t[0] = t[1]; t[1] = x; }
  }
}

// K1: gather sel columns (transposed for uniform/scalar reads) + per-pair norms.
__global__ void gather_sel_kernel(const float* __restrict__ f1,
                                  const void* __restrict__ pairs,
                                  float* __restrict__ sel_t,
                                  float* __restrict__ n_p) {
  __shared__ float red[4][64];
  __shared__ int s_idx[64];
  const int tid = threadIdx.x;
  if (tid < 64) {
    const long long* ll = (const long long*)pairs;
    const int* ii = (const int*)pairs;
    // Detect int64 vs int32 index layout: int32 pairs reinterpreted as int64
    // are ~never in [0, HW_). Only reads first 64 bytes (safe for both).
    bool is64 = true;
    for (int t = 0; t < 8; ++t) {
      long long v = ll[t];
      if (v < 0 || v >= (long long)HW_) is64 = false;
    }
    s_idx[tid] = is64 ? (int)ll[2 * tid] : ii[2 * tid];
  }
  __syncthreads();
  const int p = tid & 63, cq = tid >> 6;
  const int idx = s_idx[p];
  float nrm = 0.0f;
  for (int c = cq * 64; c < cq * 64 + 64; ++c) {
    float v = f1[(size_t)c * HW_ + idx];
    sel_t[c * 64 + p] = v;          // transposed: [c][p]
    nrm = fmaf(v, v, nrm);
  }
  red[cq][p] = nrm;
  __syncthreads();
  if (tid < 64) n_p[tid] = red[0][tid] + red[1][tid] + red[2][tid] + red[3][tid];
}

// K2: fused distance + per-block per-pair top-5.
// One block = 256 columns, one thread = one column, 64 fp32 accumulators.
__global__ __launch_bounds__(256, 2) void dist_topk_kernel(
    const float* __restrict__ f2, const float* __restrict__ sel_t,
    const float* __restrict__ n_p, float* __restrict__ cand) {
  __shared__ float dtile[64 * 256];   // exactly 64 KB, XOR-swizzled columns
  const int tid = threadIdx.x;
  const int j = blockIdx.x * 256 + tid;

  float acc[64];
#pragma unroll
  for (int p = 0; p < 64; ++p) acc[p] = 0.0f;
  float nj = 0.0f;

  const float* __restrict__ col = f2 + j;
  for (int c = 0; c < C_; c += 4) {
    float v0 = col[(size_t)(c + 0) * HW_];
    float v1 = col[(size_t)(c + 1) * HW_];
    float v2 = col[(size_t)(c + 2) * HW_];
    float v3 = col[(size_t)(c + 3) * HW_];
    nj = fmaf(v0, v0, nj); nj = fmaf(v1, v1, nj);
    nj = fmaf(v2, v2, nj); nj = fmaf(v3, v3, nj);
    const float* __restrict__ s0 = sel_t + (c + 0) * 64;  // uniform -> s_load
    const float* __restrict__ s1 = sel_t + (c + 1) * 64;
    const float* __restrict__ s2 = sel_t + (c + 2) * 64;
    const float* __restrict__ s3 = sel_t + (c + 3) * 64;
#pragma unroll
    for (int p = 0; p < 64; ++p) {
      float a = acc[p];
      a = fmaf(s0[p], v0, a);
      a = fmaf(s1[p], v1, a);
      a = fmaf(s2[p], v2, a);
      a = fmaf(s3[p], v3, a);
      acc[p] = a;
    }
  }

  // d = relu(n_p + n_j - 2*dot) -> LDS (XOR swizzle keeps both phases 2-way max)
#pragma unroll
  for (int p = 0; p < 64; ++p) {
    float d = n_p[p] + nj - 2.0f * acc[p];
    dtile[p * 256 + (tid ^ (p & 31))] = fmaxf(d, 0.0f);
  }
  __syncthreads();

  // per-pair top-5 over this block's 256 columns: 4 threads per pair
  const int pp = tid & 63, q = tid >> 6;
  float t5[5] = {SENT, SENT, SENT, SENT, SENT};
#pragma unroll 4
  for (int i = 0; i < 64; ++i) {
    float v = dtile[pp * 256 + ((q * 64 + i) ^ (pp & 31))];
    top5_insert(t5, v);
  }
  __syncthreads();
#pragma unroll
  for (int k = 0; k < 5; ++k) dtile[tid * 5 + k] = t5[k];
  __syncthreads();
  if (tid < 64) {
    float m[5] = {SENT, SENT, SENT, SENT, SENT};
    for (int q2 = 0; q2 < 4; ++q2)
#pragma unroll
      for (int k = 0; k < 5; ++k) top5_insert(m, dtile[(q2 * 64 + tid) * 5 + k]);
    float* cc = cand + (size_t)blockIdx.x * (NP_ * 5) + tid * 5;
#pragma unroll
    for (int k = 0; k < 5; ++k) cc[k] = m[k];
  }
}

// K3: reduce 1024 blocks' candidates -> per-pair mean of 5 smallest.
__global__ void topk_reduce_kernel(const float* __restrict__ cand,
                                   float* __restrict__ mean5) {
  __shared__ float lds[256 * 5];
  const int p = blockIdx.x, tid = threadIdx.x;
  float t5[5] = {SENT, SENT, SENT, SENT, SENT};
  for (int b = tid; b < NBLK_; b += 256) {
    const float* cc = cand + (size_t)b * (NP_ * 5) + p * 5;
#pragma unroll
    for (int k = 0; k < 5; ++k) top5_insert(t5, cc[k]);
  }
#pragma unroll
  for (int k = 0; k < 5; ++k) lds[tid * 5 + k] = t5[k];
  __syncthreads();
  float m2[5] = {SENT, SENT, SENT, SENT, SENT};
  if (tid < 32) {
    for (int t2 = tid * 8; t2 < tid * 8 + 8; ++t2)
#pragma unroll
      for (int k = 0; k < 5; ++k) top5_insert(m2, lds[t2 * 5 + k]);
  }
  __syncthreads();
  if (tid < 32) {
#pragma unroll
    for (int k = 0; k < 5; ++k) lds[tid * 5 + k] = m2[k];
  }
  __syncthreads();
  if (tid == 0) {
    float f[5] = {SENT, SENT, SENT, SENT, SENT};
    for (int t2 = 0; t2 < 32; ++t2)
#pragma unroll
      for (int k = 0; k < 5; ++k) top5_insert(f, lds[t2 * 5 + k]);
    mean5[p] = (f[0] + f[1] + f[2] + f[3] + f[4]) * 0.2f;
  }
}

// K4: final sum over pairs (deterministic, no atomics).
__global__ void final_sum_kernel(const float* __restrict__ mean5,
                                 float* __restrict__ out) {
  const int tid = threadIdx.x;  // 64 threads = 1 wave
  float v = mean5[tid];
  for (int off = 32; off > 0; off >>= 1) v += __shfl_down(v, off);
  if (tid == 0) out[0] = v * (1.0f / 64.0f);
}

extern "C" void kernel_launch(void* const* d_in, const int* in_sizes, int n_in,
                              void* d_out, int out_size, void* d_ws, size_t ws_size,
                              hipStream_t stream) {
  const float* f1 = (const float*)d_in[0];
  const float* f2 = (const float*)d_in[1];
  const void* pairs = d_in[2];
  float* out = (float*)d_out;
  float* ws = (float*)d_ws;

  float* sel_t = ws;                    // 256*64            = 16384 floats
  float* n_p   = ws + 16384;            // 64
  float* cand  = ws + 16448;            // 1024*64*5         = 327680
  float* mean5 = ws + 16448 + 327680;   // 64

  gather_sel_kernel<<<1, 256, 0, stream>>>(f1, pairs, sel_t, n_p);
  dist_topk_kernel<<<NBLK_, 256, 0, stream>>>(f2, sel_t, n_p, cand);
  topk_reduce_kernel<<<NP_, 256, 0, stream>>>(cand, mean5);
  final_sum_kernel<<<1, 64, 0, stream>>>(mean5, out);
}

// Round 2
// 173.090 us; speedup vs baseline: 2.0000x; 2.0000x over previous
//
#include <hip/hip_runtime.h>
#include <hip/hip_bf16.h>

#define HW_   262144   // 512*512
#define C_    256
#define NP_   64
#define NBLK_ 1024     // HW_/256 cols per block
#define SENT  3.0e38f

__device__ __forceinline__ void top5_insert(float (&t)[5], float v) {
  if (v < t[4]) {
    t[4] = v;
    if (t[4] < t[3]) { float x = t[3]; t[3] = t[4]; t[4] = x; }
    if (t[3] < t[2]) { float x = t[2]; t[2] = t[3]; t[3] = x; }
    if (t[2] < t[1]) { float x = t[1]; t[1] = t[2]; t[2] = x; }
    if (t[1] < t[0]) { float x = t[0]; t[0] = t[1]; t[1] = x; }
  }
}

// K1: one block per pair; thread t handles channel c=t. Coalesced-enough,
// massively parallel (64 blocks), also produces per-pair squared norm.
__global__ void gather_sel_kernel(const float* __restrict__ f1,
                                  const void* __restrict__ pairs,
                                  float* __restrict__ sel_t,   // [c][64]
                                  float* __restrict__ n_p) {
  __shared__ float red[256];
  __shared__ int sidx;
  const int p = blockIdx.x, t = threadIdx.x;
  if (t == 0) {
    const long long* ll = (const long long*)pairs;
    const int* ii = (const int*)pairs;
    bool is64 = true;
    for (int k = 0; k < 8; ++k) {
      long long v = ll[k];
      if (v < 0 || v >= (long long)HW_) is64 = false;
    }
    sidx = is64 ? (int)ll[2 * p] : ii[2 * p];
  }
  __syncthreads();
  const int idx = sidx;
  float v = f1[(size_t)t * HW_ + idx];
  sel_t[t * 64 + p] = v;
  red[t] = v * v;
  __syncthreads();
  for (int s = 128; s > 0; s >>= 1) {
    if (t < s) red[t] += red[t + s];
    __syncthreads();
  }
  if (t == 0) n_p[p] = red[0];
}

// K2: 512 threads = 8 waves. Wave w owns pairs w*8..w*8+7; lane l owns cols
// j0+4l..j0+4l+3. sel in LDS (wave-uniform b128 broadcasts); f2 via prefetched
// float4 loads; 64-KB LDS reused for the d-tile transpose in the top-5 phase.
__global__ __launch_bounds__(512, 4) void dist_topk_kernel(
    const float* __restrict__ f2, const float* __restrict__ sel_t,
    const float* __restrict__ n_p, float* __restrict__ cand) {
  __shared__ float smem[64 * 256];   // 64 KB union: selL[c][64] then dtile[p][256]
  const int tid = threadIdx.x;
  const int w = tid >> 6, l = tid & 63;
  const int p0 = w * 8;
  const int j0 = blockIdx.x * 256;

  // stage sel (16384 floats) into LDS, coalesced float4
  {
    const float4* s4 = (const float4*)sel_t;
    float4* d4 = (float4*)smem;
#pragma unroll
    for (int i = 0; i < 8; ++i) d4[tid + i * 512] = s4[tid + i * 512];
  }
  __syncthreads();

  float acc[8][4];
#pragma unroll
  for (int p = 0; p < 8; ++p)
#pragma unroll
    for (int m = 0; m < 4; ++m) acc[p][m] = 0.0f;
  float nj[4] = {0.f, 0.f, 0.f, 0.f};

  const float* __restrict__ colp = f2 + j0 + 4 * l;
  float4 cur[4], nxt[4];
#pragma unroll
  for (int q = 0; q < 4; ++q) cur[q] = *(const float4*)(colp + (size_t)q * HW_);

  for (int cb = 0; cb < C_; cb += 4) {
    if (cb + 4 < C_) {
#pragma unroll
      for (int q = 0; q < 4; ++q)
        nxt[q] = *(const float4*)(colp + (size_t)(cb + 4 + q) * HW_);
    }
#pragma unroll
    for (int q = 0; q < 4; ++q) {
      const int c = cb + q;
      const float4 s0 = *(const float4*)(&smem[c * 64 + p0]);
      const float4 s1 = *(const float4*)(&smem[c * 64 + p0 + 4]);
      const float4 v = cur[q];
      nj[0] = fmaf(v.x, v.x, nj[0]);
      nj[1] = fmaf(v.y, v.y, nj[1]);
      nj[2] = fmaf(v.z, v.z, nj[2]);
      nj[3] = fmaf(v.w, v.w, nj[3]);
      const float sv[8] = {s0.x, s0.y, s0.z, s0.w, s1.x, s1.y, s1.z, s1.w};
#pragma unroll
      for (int p = 0; p < 8; ++p) {
        acc[p][0] = fmaf(sv[p], v.x, acc[p][0]);
        acc[p][1] = fmaf(sv[p], v.y, acc[p][1]);
        acc[p][2] = fmaf(sv[p], v.z, acc[p][2]);
        acc[p][3] = fmaf(sv[p], v.w, acc[p][3]);
      }
    }
#pragma unroll
    for (int q = 0; q < 4; ++q) cur[q] = nxt[q];
  }

  // d-tile: relu(n_p + n_j - 2*dot) -> swizzled LDS (reuse sel buffer)
  __syncthreads();
#pragma unroll
  for (int p = 0; p < 8; ++p) {
    const int pp = p0 + p;
    const float np = n_p[pp];
#pragma unroll
    for (int m = 0; m < 4; ++m) {
      const int col = 4 * l + m;
      float d = np + nj[m] - 2.0f * acc[p][m];
      smem[pp * 256 + (col ^ (pp & 31))] = fmaxf(d, 0.0f);
    }
  }
  __syncthreads();

  // per-pair top-5 over this block's 256 cols: 8 threads per pair, 32 cols each
  const int pp = tid & 63, q = tid >> 6;
  float t5[5] = {SENT, SENT, SENT, SENT, SENT};
#pragma unroll 4
  for (int i = 0; i < 32; ++i) {
    const int col = q * 32 + i;
    float v = smem[pp * 256 + (col ^ (pp & 31))];
    top5_insert(t5, v);
  }
  __syncthreads();
#pragma unroll
  for (int k = 0; k < 5; ++k) smem[tid * 5 + k] = t5[k];
  __syncthreads();
  if (tid < 64) {
    float m[5] = {SENT, SENT, SENT, SENT, SENT};
    for (int g = 0; g < 8; ++g)
#pragma unroll
      for (int k = 0; k < 5; ++k) top5_insert(m, smem[(g * 64 + tid) * 5 + k]);
    float* cc = cand + (size_t)blockIdx.x * (NP_ * 5) + tid * 5;
#pragma unroll
    for (int k = 0; k < 5; ++k) cc[k] = m[k];
  }
}

// K3: reduce 1024 blocks' candidates -> per-pair mean of 5 smallest.
__global__ void topk_reduce_kernel(const float* __restrict__ cand,
                                   float* __restrict__ mean5) {
  __shared__ float lds[256 * 5];
  const int p = blockIdx.x, tid = threadIdx.x;
  float t5[5] = {SENT, SENT, SENT, SENT, SENT};
  for (int b = tid; b < NBLK_; b += 256) {
    const float* cc = cand + (size_t)b * (NP_ * 5) + p * 5;
#pragma unroll
    for (int k = 0; k < 5; ++k) top5_insert(t5, cc[k]);
  }
#pragma unroll
  for (int k = 0; k < 5; ++k) lds[tid * 5 + k] = t5[k];
  __syncthreads();
  float m2[5] = {SENT, SENT, SENT, SENT, SENT};
  if (tid < 32) {
    for (int t2 = tid * 8; t2 < tid * 8 + 8; ++t2)
#pragma unroll
      for (int k = 0; k < 5; ++k) top5_insert(m2, lds[t2 * 5 + k]);
  }
  __syncthreads();
  if (tid < 32) {
#pragma unroll
    for (int k = 0; k < 5; ++k) lds[tid * 5 + k] = m2[k];
  }
  __syncthreads();
  if (tid == 0) {
    float f[5] = {SENT, SENT, SENT, SENT, SENT};
    for (int t2 = 0; t2 < 32; ++t2)
#pragma unroll
      for (int k = 0; k < 5; ++k) top5_insert(f, lds[t2 * 5 + k]);
    mean5[p] = (f[0] + f[1] + f[2] + f[3] + f[4]) * 0.2f;
  }
}

// K4: final sum over pairs (deterministic, no atomics).
__global__ void final_sum_kernel(const float* __restrict__ mean5,
                                 float* __restrict__ out) {
  const int tid = threadIdx.x;  // 64 threads = 1 wave
  float v = mean5[tid];
  for (int off = 32; off > 0; off >>= 1) v += __shfl_down(v, off);
  if (tid == 0) out[0] = v * (1.0f / 64.0f);
}

extern "C" void kernel_launch(void* const* d_in, const int* in_sizes, int n_in,
                              void* d_out, int out_size, void* d_ws, size_t ws_size,
                              hipStream_t stream) {
  const float* f1 = (const float*)d_in[0];
  const float* f2 = (const float*)d_in[1];
  const void* pairs = d_in[2];
  float* out = (float*)d_out;
  float* ws = (float*)d_ws;

  float* sel_t = ws;                    // 256*64            = 16384 floats
  float* n_p   = ws + 16384;            // 64
  float* cand  = ws + 16448;            // 1024*64*5         = 327680
  float* mean5 = ws + 16448 + 327680;   // 64

  gather_sel_kernel<<<NP_, 256, 0, stream>>>(f1, pairs, sel_t, n_p);
  dist_topk_kernel<<<NBLK_, 512, 0, stream>>>(f2, sel_t, n_p, cand);
  topk_reduce_kernel<<<NP_, 256, 0, stream>>>(cand, mean5);
  final_sum_kernel<<<1, 64, 0, stream>>>(mean5, out);
}

// Round 3
// 90.464 us; speedup vs baseline: 3.8267x; 1.9134x over previous
//
#include <hip/hip_runtime.h>
#include <hip/hip_bf16.h>

#define HW_   262144   // 512*512
#define C_    256
#define NP_   64
#define NBLK_ 1024     // HW_/256 cols per block
#define SENT  3.0e38f

typedef __attribute__((ext_vector_type(8))) __bf16 bf16x8;
typedef __attribute__((ext_vector_type(4))) float f32x4;

__device__ __forceinline__ void top5_insert(float (&t)[5], float v) {
  if (v < t[4]) {
    t[4] = v;
    if (t[4] < t[3]) { float x = t[3]; t[3] = t[4]; t[4] = x; }
    if (t[3] < t[2]) { float x = t[2]; t[2] = t[3]; t[3] = x; }
    if (t[2] < t[1]) { float x = t[1]; t[1] = t[2]; t[2] = x; }
    if (t[1] < t[0]) { float x = t[0]; t[0] = t[1]; t[1] = x; }
  }
}

// K1: one block per pair; thread t = channel. Emits bf16 sel [pair][chan]
// (row-major, MFMA A layout source) + fp32 norms.
__global__ void gather_sel_kernel(const float* __restrict__ f1,
                                  const void* __restrict__ pairs,
                                  unsigned short* __restrict__ selb,  // [64][256] bf16 bits
                                  float* __restrict__ n_p) {
  __shared__ float red[256];
  __shared__ int sidx;
  const int p = blockIdx.x, t = threadIdx.x;
  if (t == 0) {
    const long long* ll = (const long long*)pairs;
    const int* ii = (const int*)pairs;
    bool is64 = true;
    for (int k = 0; k < 8; ++k) {
      long long v = ll[k];
      if (v < 0 || v >= (long long)HW_) is64 = false;
    }
    sidx = is64 ? (int)ll[2 * p] : ii[2 * p];
  }
  __syncthreads();
  const int idx = sidx;
  float v = f1[(size_t)t * HW_ + idx];
  __bf16 b = (__bf16)v;
  selb[p * 256 + t] = __builtin_bit_cast(unsigned short, b);
  red[t] = v * v;
  __syncthreads();
  for (int s = 128; s > 0; s >>= 1) {
    if (t < s) red[t] += red[t + s];
    __syncthreads();
  }
  if (t == 0) n_p[p] = red[0];
}

// K2: MFMA GEMM (64 x 262144 x 256) fused with norms + relu + per-block top-5.
// 256 threads = 4 waves; wave w owns cols [j0+64w, j0+64w+64). A in swizzled
// LDS (staged once); B streamed global->reg->bf16 (no K-loop barriers).
__global__ __launch_bounds__(256, 2) void dist_topk_kernel(
    const float* __restrict__ f2, const unsigned short* __restrict__ selb,
    const float* __restrict__ n_p, float* __restrict__ cand) {
  __shared__ float smem[64 * 256];   // 64 KB; bytes [0,32K) double as A-tile
  char* smemB = (char*)smem;
  const int tid = threadIdx.x;
  const int w = tid >> 6, lane = tid & 63;
  const int m_l = lane & 15, kq = lane >> 4;
  const int j0 = blockIdx.x * 256;

  // ---- stage A (64x256 bf16 = 32KB) into LDS, byte ^= ((m&7)<<4) swizzle ----
  {
    const uint4* src = (const uint4*)selb;            // 2048 x 16B
    const int m = tid >> 2, c4 = tid & 3;
#pragma unroll
    for (int i = 0; i < 8; ++i) {
      uint4 vv = src[m * 32 + c4 * 8 + i];
      unsigned off = (unsigned)(m * 512 + c4 * 128 + i * 16) ^ ((m & 7) << 4);
      *(uint4*)(smemB + off) = vv;
    }
  }
  __syncthreads();

  // ---- per-lane B pointers: element (k = kq*8+e, col = j0+64w+m_l+16nt) ----
  const float* bp[8];
#pragma unroll
  for (int e = 0; e < 8; ++e)
    bp[e] = f2 + (size_t)(kq * 8 + e) * HW_ + (j0 + w * 64 + m_l);

  f32x4 acc[4][4];
#pragma unroll
  for (int mt = 0; mt < 4; ++mt)
#pragma unroll
    for (int nt = 0; nt < 4; ++nt) acc[mt][nt] = (f32x4){0.f, 0.f, 0.f, 0.f};
  float njp[4] = {0.f, 0.f, 0.f, 0.f};

  float b0[32], b1[32];
#define LOADB(BUF)                                     \
  _Pragma("unroll") for (int nt = 0; nt < 4; ++nt)     \
  _Pragma("unroll") for (int e = 0; e < 8; ++e)        \
      BUF[nt * 8 + e] = bp[e][nt * 16];
#define ADVANCE()                                      \
  _Pragma("unroll") for (int e = 0; e < 8; ++e) bp[e] += (size_t)32 * HW_;

  LOADB(b0); ADVANCE();

#define STEP(CUR, NXT, S, PF)                                                   \
  {                                                                             \
    if (PF) { LOADB(NXT); ADVANCE(); }                                          \
    bf16x8 afr[4];                                                              \
    _Pragma("unroll") for (int mt = 0; mt < 4; ++mt) {                          \
      unsigned offA =                                                           \
          (unsigned)((mt * 16 + m_l) * 512 + kq * 16 + (S) * 64) ^              \
          ((m_l & 7) << 4);                                                     \
      afr[mt] = *(const bf16x8*)(smemB + offA);                                 \
    }                                                                           \
    bf16x8 bfr[4];                                                              \
    _Pragma("unroll") for (int nt = 0; nt < 4; ++nt) {                          \
      _Pragma("unroll") for (int e = 0; e < 8; ++e) {                           \
        float v = CUR[nt * 8 + e];                                              \
        njp[nt] = fmaf(v, v, njp[nt]);                                          \
        bfr[nt][e] = (__bf16)v;                                                 \
      }                                                                         \
    }                                                                           \
    _Pragma("unroll") for (int mt = 0; mt < 4; ++mt)                            \
      _Pragma("unroll") for (int nt = 0; nt < 4; ++nt)                          \
        acc[mt][nt] = __builtin_amdgcn_mfma_f32_16x16x32_bf16(                  \
            afr[mt], bfr[nt], acc[mt][nt], 0, 0, 0);                            \
  }

  STEP(b0, b1, 0, 1) STEP(b1, b0, 1, 1) STEP(b0, b1, 2, 1) STEP(b1, b0, 3, 1)
  STEP(b0, b1, 4, 1) STEP(b1, b0, 5, 1) STEP(b0, b1, 6, 1) STEP(b1, b0, 7, 0)
#undef STEP
#undef LOADB
#undef ADVANCE

  // ---- finalize column norms across the 4 k-groups sharing a column ----
  float njc[4];
#pragma unroll
  for (int nt = 0; nt < 4; ++nt) {
    float v = njp[nt];
    v += __shfl_xor(v, 16);
    v += __shfl_xor(v, 32);
    njc[nt] = v;
  }

  __syncthreads();   // all waves done reading A; smem becomes the d-tile

  // ---- d = relu(n_p + n_j - 2*dot) -> swizzled LDS ----
  // C/D frag: row(pair) = mt*16 + kq*4 + r, col = w*64 + nt*16 + m_l
#pragma unroll
  for (int mt = 0; mt < 4; ++mt) {
#pragma unroll
    for (int r = 0; r < 4; ++r) {
      const int pair = mt * 16 + kq * 4 + r;
      const float np = n_p[pair];
#pragma unroll
      for (int nt = 0; nt < 4; ++nt) {
        const int col = w * 64 + nt * 16 + m_l;
        float d = np + njc[nt] - 2.0f * acc[mt][nt][r];
        smem[pair * 256 + (col ^ (pair & 31))] = fmaxf(d, 0.0f);
      }
    }
  }
  __syncthreads();

  // ---- per-pair top-5 over this block's 256 cols: 4 threads/pair ----
  const int pp = tid & 63, q = tid >> 6;
  float t5[5] = {SENT, SENT, SENT, SENT, SENT};
#pragma unroll 4
  for (int i = 0; i < 64; ++i) {
    float v = smem[pp * 256 + ((q * 64 + i) ^ (pp & 31))];
    top5_insert(t5, v);
  }
  __syncthreads();
#pragma unroll
  for (int k = 0; k < 5; ++k) smem[tid * 5 + k] = t5[k];
  __syncthreads();
  if (tid < 64) {
    float m5[5] = {SENT, SENT, SENT, SENT, SENT};
    for (int g = 0; g < 4; ++g)
#pragma unroll
      for (int k = 0; k < 5; ++k) top5_insert(m5, smem[(g * 64 + tid) * 5 + k]);
    float* cc = cand + (size_t)blockIdx.x * (NP_ * 5) + tid * 5;
#pragma unroll
    for (int k = 0; k < 5; ++k) cc[k] = m5[k];
  }
}

// K3: reduce 1024 blocks' candidates -> per-pair mean of 5 smallest.
__global__ void topk_reduce_kernel(const float* __restrict__ cand,
                                   float* __restrict__ mean5) {
  __shared__ float lds[256 * 5];
  const int p = blockIdx.x, tid = threadIdx.x;
  float t5[5] = {SENT, SENT, SENT, SENT, SENT};
  for (int b = tid; b < NBLK_; b += 256) {
    const float* cc = cand + (size_t)b * (NP_ * 5) + p * 5;
#pragma unroll
    for (int k = 0; k < 5; ++k) top5_insert(t5, cc[k]);
  }
#pragma unroll
  for (int k = 0; k < 5; ++k) lds[tid * 5 + k] = t5[k];
  __syncthreads();
  float m2[5] = {SENT, SENT, SENT, SENT, SENT};
  if (tid < 32) {
    for (int t2 = tid * 8; t2 < tid * 8 + 8; ++t2)
#pragma unroll
      for (int k = 0; k < 5; ++k) top5_insert(m2, lds[t2 * 5 + k]);
  }
  __syncthreads();
  if (tid < 32) {
#pragma unroll
    for (int k = 0; k < 5; ++k) lds[tid * 5 + k] = m2[k];
  }
  __syncthreads();
  if (tid == 0) {
    float f[5] = {SENT, SENT, SENT, SENT, SENT};
    for (int t2 = 0; t2 < 32; ++t2)
#pragma unroll
      for (int k = 0; k < 5; ++k) top5_insert(f, lds[t2 * 5 + k]);
    mean5[p] = (f[0] + f[1] + f[2] + f[3] + f[4]) * 0.2f;
  }
}

// K4: final sum over pairs (deterministic).
__global__ void final_sum_kernel(const float* __restrict__ mean5,
                                 float* __restrict__ out) {
  const int tid = threadIdx.x;  // 1 wave
  float v = mean5[tid];
  for (int off = 32; off > 0; off >>= 1) v += __shfl_down(v, off);
  if (tid == 0) out[0] = v * (1.0f / 64.0f);
}

extern "C" void kernel_launch(void* const* d_in, const int* in_sizes, int n_in,
                              void* d_out, int out_size, void* d_ws, size_t ws_size,
                              hipStream_t stream) {
  const float* f1 = (const float*)d_in[0];
  const float* f2 = (const float*)d_in[1];
  const void* pairs = d_in[2];
  float* out = (float*)d_out;
  float* ws = (float*)d_ws;

  float*          n_p   = ws;                         // 64 f
  unsigned short* selb  = (unsigned short*)(ws + 64); // 16384 ushort (32KB)
  float*          cand  = ws + 64 + 8192;             // 1024*64*5 f
  float*          mean5 = ws + 64 + 8192 + 327680;    // 64 f

  gather_sel_kernel<<<NP_, 256, 0, stream>>>(f1, pairs, selb, n_p);
  dist_topk_kernel<<<NBLK_, 256, 0, stream>>>(f2, selb, n_p, cand);
  topk_reduce_kernel<<<NP_, 256, 0, stream>>>(cand, mean5);
  final_sum_kernel<<<1, 64, 0, stream>>>(mean5, out);
}

// Round 4
// 83.741 us; speedup vs baseline: 4.1340x; 1.0803x over previous
//
#include <hip/hip_runtime.h>
#include <hip/hip_bf16.h>

#define HW_   262144   // 512*512
#define C_    256
#define NP_   64
#define NBLK_ 1024     // HW_/256 cols per block
#define SENT  3.0e38f

typedef __attribute__((ext_vector_type(8))) __bf16 bf16x8;
typedef __attribute__((ext_vector_type(4))) float f32x4;

__device__ __forceinline__ void top5_insert(float (&t)[5], float v) {
  if (v < t[4]) {
    t[4] = v;
    if (t[4] < t[3]) { float x = t[3]; t[3] = t[4]; t[4] = x; }
    if (t[3] < t[2]) { float x = t[2]; t[2] = t[3]; t[3] = x; }
    if (t[2] < t[1]) { float x = t[1]; t[1] = t[2]; t[2] = x; }
    if (t[1] < t[0]) { float x = t[0]; t[0] = t[1]; t[1] = x; }
  }
}

// K1: one block per pair; thread t = channel. Emits bf16 sel [pair][chan] + fp32 norms.
__global__ void gather_sel_kernel(const float* __restrict__ f1,
                                  const void* __restrict__ pairs,
                                  unsigned short* __restrict__ selb,  // [64][256] bf16 bits
                                  float* __restrict__ n_p) {
  __shared__ float red[256];
  __shared__ int sidx;
  const int p = blockIdx.x, t = threadIdx.x;
  if (t == 0) {
    const long long* ll = (const long long*)pairs;
    const int* ii = (const int*)pairs;
    bool is64 = true;
    for (int k = 0; k < 8; ++k) {
      long long v = ll[k];
      if (v < 0 || v >= (long long)HW_) is64 = false;
    }
    sidx = is64 ? (int)ll[2 * p] : ii[2 * p];
  }
  __syncthreads();
  const int idx = sidx;
  float v = f1[(size_t)t * HW_ + idx];
  __bf16 b = (__bf16)v;
  selb[p * 256 + t] = __builtin_bit_cast(unsigned short, b);
  red[t] = v * v;
  __syncthreads();
  for (int s = 128; s > 0; s >>= 1) {
    if (t < s) red[t] += red[t + s];
    __syncthreads();
  }
  if (t == 0) n_p[p] = red[0];
}

// K2: MFMA GEMM (64 x 262144 x 256) fused with norms + relu + per-block top-5.
// 512 threads = 8 waves; wave w owns cols [j0+32w, j0+32w+32) (2 N-tiles).
// Halved per-thread state vs round 3 -> VGPR<=128 -> 16 waves/CU (4/SIMD).
__global__ __launch_bounds__(512, 4) void dist_topk_kernel(
    const float* __restrict__ f2, const unsigned short* __restrict__ selb,
    const float* __restrict__ n_p, float* __restrict__ cand) {
  __shared__ float smem[64 * 256];   // 64 KB; bytes [0,32K) double as A-tile
  char* smemB = (char*)smem;
  const int tid = threadIdx.x;
  const int w = tid >> 6, lane = tid & 63;
  const int m_l = lane & 15, kq = lane >> 4;
  const int j0 = blockIdx.x * 256;

  // ---- stage A (64x256 bf16 = 32KB) into LDS, byte ^= ((row&7)<<4) swizzle ----
  {
    const uint4* src = (const uint4*)selb;            // 2048 x 16B
#pragma unroll
    for (int i = 0; i < 4; ++i) {
      const int idx = i * 512 + tid;
      const int m = idx >> 5;                          // 32 uint4 per 512B row
      unsigned off = (unsigned)(idx * 16) ^ ((m & 7) << 4);
      *(uint4*)(smemB + off) = src[idx];
    }
  }
  __syncthreads();

  // ---- per-lane B pointers: element (k = kq*8+e, col = j0+32w+m_l+16nt) ----
  const float* bp[8];
#pragma unroll
  for (int e = 0; e < 8; ++e)
    bp[e] = f2 + (size_t)(kq * 8 + e) * HW_ + (j0 + w * 32 + m_l);

  f32x4 acc[4][2];
#pragma unroll
  for (int mt = 0; mt < 4; ++mt)
#pragma unroll
    for (int nt = 0; nt < 2; ++nt) acc[mt][nt] = (f32x4){0.f, 0.f, 0.f, 0.f};
  float njp[2] = {0.f, 0.f};

  float b0[16], b1[16];
#define LOADB(BUF)                                     \
  _Pragma("unroll") for (int nt = 0; nt < 2; ++nt)     \
  _Pragma("unroll") for (int e = 0; e < 8; ++e)        \
      BUF[nt * 8 + e] = bp[e][nt * 16];
#define ADVANCE()                                      \
  _Pragma("unroll") for (int e = 0; e < 8; ++e) bp[e] += (size_t)32 * HW_;

  LOADB(b0); ADVANCE();

#define STEP(CUR, NXT, S, PF)                                                   \
  {                                                                             \
    if (PF) { LOADB(NXT); ADVANCE(); }                                          \
    bf16x8 afr[4];                                                              \
    _Pragma("unroll") for (int mt = 0; mt < 4; ++mt) {                          \
      unsigned offA =                                                           \
          (unsigned)((mt * 16 + m_l) * 512 + kq * 16 + (S) * 64) ^              \
          ((m_l & 7) << 4);                                                     \
      afr[mt] = *(const bf16x8*)(smemB + offA);                                 \
    }                                                                           \
    bf16x8 bfr[2];                                                              \
    _Pragma("unroll") for (int nt = 0; nt < 2; ++nt) {                          \
      _Pragma("unroll") for (int e = 0; e < 8; ++e) {                           \
        float v = CUR[nt * 8 + e];                                              \
        njp[nt] = fmaf(v, v, njp[nt]);                                          \
        bfr[nt][e] = (__bf16)v;                                                 \
      }                                                                         \
    }                                                                           \
    _Pragma("unroll") for (int mt = 0; mt < 4; ++mt)                            \
      _Pragma("unroll") for (int nt = 0; nt < 2; ++nt)                          \
        acc[mt][nt] = __builtin_amdgcn_mfma_f32_16x16x32_bf16(                  \
            afr[mt], bfr[nt], acc[mt][nt], 0, 0, 0);                            \
  }

  STEP(b0, b1, 0, 1) STEP(b1, b0, 1, 1) STEP(b0, b1, 2, 1) STEP(b1, b0, 3, 1)
  STEP(b0, b1, 4, 1) STEP(b1, b0, 5, 1) STEP(b0, b1, 6, 1) STEP(b1, b0, 7, 0)
#undef STEP
#undef LOADB
#undef ADVANCE

  // ---- finalize column norms across the 4 k-groups sharing a column ----
  float njc[2];
#pragma unroll
  for (int nt = 0; nt < 2; ++nt) {
    float v = njp[nt];
    v += __shfl_xor(v, 16);
    v += __shfl_xor(v, 32);
    njc[nt] = v;
  }

  __syncthreads();   // all waves done reading A; smem becomes the d-tile

  // ---- d = relu(n_p + n_j - 2*dot) -> swizzled LDS ----
  // C/D frag: row(pair) = mt*16 + kq*4 + r, col = w*32 + nt*16 + m_l
#pragma unroll
  for (int mt = 0; mt < 4; ++mt) {
#pragma unroll
    for (int r = 0; r < 4; ++r) {
      const int pair = mt * 16 + kq * 4 + r;
      const float np = n_p[pair];
#pragma unroll
      for (int nt = 0; nt < 2; ++nt) {
        const int col = w * 32 + nt * 16 + m_l;
        float d = np + njc[nt] - 2.0f * acc[mt][nt][r];
        smem[pair * 256 + (col ^ (pair & 31))] = fmaxf(d, 0.0f);
      }
    }
  }
  __syncthreads();

  // ---- per-pair top-5 over this block's 256 cols: 8 threads/pair ----
  const int pp = tid & 63, q = tid >> 6;
  float t5[5] = {SENT, SENT, SENT, SENT, SENT};
#pragma unroll 4
  for (int i = 0; i < 32; ++i) {
    const int col = q * 32 + i;
    float v = smem[pp * 256 + (col ^ (pp & 31))];
    top5_insert(t5, v);
  }
  __syncthreads();
#pragma unroll
  for (int k = 0; k < 5; ++k) smem[tid * 5 + k] = t5[k];
  __syncthreads();
  if (tid < 64) {
    float m5[5] = {SENT, SENT, SENT, SENT, SENT};
    for (int g = 0; g < 8; ++g)
#pragma unroll
      for (int k = 0; k < 5; ++k) top5_insert(m5, smem[(g * 64 + tid) * 5 + k]);
    float* cc = cand + (size_t)blockIdx.x * (NP_ * 5) + tid * 5;
#pragma unroll
    for (int k = 0; k < 5; ++k) cc[k] = m5[k];
  }
}

// K3: reduce 1024 blocks' candidates -> per-pair mean of 5 smallest.
__global__ void topk_reduce_kernel(const float* __restrict__ cand,
                                   float* __restrict__ mean5) {
  __shared__ float lds[256 * 5];
  const int p = blockIdx.x, tid = threadIdx.x;
  float t5[5] = {SENT, SENT, SENT, SENT, SENT};
  for (int b = tid; b < NBLK_; b += 256) {
    const float* cc = cand + (size_t)b * (NP_ * 5) + p * 5;
#pragma unroll
    for (int k = 0; k < 5; ++k) top5_insert(t5, cc[k]);
  }
#pragma unroll
  for (int k = 0; k < 5; ++k) lds[tid * 5 + k] = t5[k];
  __syncthreads();
  float m2[5] = {SENT, SENT, SENT, SENT, SENT};
  if (tid < 32) {
    for (int t2 = tid * 8; t2 < tid * 8 + 8; ++t2)
#pragma unroll
      for (int k = 0; k < 5; ++k) top5_insert(m2, lds[t2 * 5 + k]);
  }
  __syncthreads();
  if (tid < 32) {
#pragma unroll
    for (int k = 0; k < 5; ++k) lds[tid * 5 + k] = m2[k];
  }
  __syncthreads();
  if (tid == 0) {
    float f[5] = {SENT, SENT, SENT, SENT, SENT};
    for (int t2 = 0; t2 < 32; ++t2)
#pragma unroll
      for (int k = 0; k < 5; ++k) top5_insert(f, lds[t2 * 5 + k]);
    mean5[p] = (f[0] + f[1] + f[2] + f[3] + f[4]) * 0.2f;
  }
}

// K4: final sum over pairs (deterministic).
__global__ void final_sum_kernel(const float* __restrict__ mean5,
                                 float* __restrict__ out) {
  const int tid = threadIdx.x;  // 1 wave
  float v = mean5[tid];
  for (int off = 32; off > 0; off >>= 1) v += __shfl_down(v, off);
  if (tid == 0) out[0] = v * (1.0f / 64.0f);
}

extern "C" void kernel_launch(void* const* d_in, const int* in_sizes, int n_in,
                              void* d_out, int out_size, void* d_ws, size_t ws_size,
                              hipStream_t stream) {
  const float* f1 = (const float*)d_in[0];
  const float* f2 = (const float*)d_in[1];
  const void* pairs = d_in[2];
  float* out = (float*)d_out;
  float* ws = (float*)d_ws;

  float*          n_p   = ws;                         // 64 f
  unsigned short* selb  = (unsigned short*)(ws + 64); // 16384 ushort (32KB)
  float*          cand  = ws + 64 + 8192;             // 1024*64*5 f
  float*          mean5 = ws + 64 + 8192 + 327680;    // 64 f

  gather_sel_kernel<<<NP_, 256, 0, stream>>>(f1, pairs, selb, n_p);
  dist_topk_kernel<<<NBLK_, 512, 0, stream>>>(f2, selb, n_p, cand);
  topk_reduce_kernel<<<NP_, 256, 0, stream>>>(cand, mean5);
  final_sum_kernel<<<1, 64, 0, stream>>>(mean5, out);
}